// Round 12
// baseline (295.466 us; speedup 1.0000x reference)
//
#include <hip/hip_runtime.h>

#define NN 50000
#define NE 600000
#define DD 128
#define NG 64

typedef unsigned int uint;
typedef unsigned short ushort;
typedef __attribute__((ext_vector_type(8))) short short8;
typedef __attribute__((ext_vector_type(4))) float f4;

// ---------------- bf16 helpers ----------------

__device__ __forceinline__ float bf_lo(uint v) { return __uint_as_float(v << 16); }
__device__ __forceinline__ float bf_hi(uint v) { return __uint_as_float(v & 0xffff0000u); }
__device__ __forceinline__ float bf2f(ushort h) { return __uint_as_float((uint)h << 16); }
__device__ __forceinline__ ushort f2bf(float f) {
    uint u = __float_as_uint(f);
    uint r = (u + 0x7fffu + ((u >> 16) & 1u)) >> 16;   // round-nearest-even
    return (ushort)r;
}

// ---------------- setup kernels ----------------

// blocks [0,586): degree histogram, int4-vectorized (4 edges/thread).
// blocks [586,610): pack W (split bf16 hi/lo into MFMA B-fragment layout).
__global__ void k_hist_wpack(const int* __restrict__ dstv, int* __restrict__ deg,
                             const float* __restrict__ W1, const float* __restrict__ W2,
                             const float* __restrict__ W3, short* __restrict__ wpk) {
    if (blockIdx.x < 586) {
        int t = blockIdx.x * 256 + threadIdx.x;    // < 150016, NE/4 = 150000
        if (t < NE / 4) {
            int4 d4 = ((const int4*)dstv)[t];
            atomicAdd(&deg[d4.x], 1);
            atomicAdd(&deg[d4.y], 1);
            atomicAdd(&deg[d4.z], 1);
            atomicAdd(&deg[d4.w], 1);
        }
    } else {
        int u = (blockIdx.x - 586) * 256 + threadIdx.x;   // < 6144
        int layer = u >> 11, g = u & 2047;
        const float* W = (layer == 0) ? W1 : (layer == 1) ? W2 : W3;
        short* base = wpk + (size_t)layer * 32768;
        int nt = g >> 8, kk = (g >> 6) & 3, lane = g & 63;
        int k0 = kk * 32 + (lane >> 4) * 8;
        int n = nt * 16 + (lane & 15);
        #pragma unroll
        for (int j = 0; j < 8; ++j) {
            float w = W[(size_t)(k0 + j) * DD + n];
            ushort h = f2bf(w);
            base[g * 8 + j] = (short)h;
            base[16384 + g * 8 + j] = (short)f2bf(w - bf2f(h));
        }
    }
}

// Rows padded to multiples of 8 (pad cols -> zero row NN). rp is over PADDED
// sizes; dinv over true size (deg+1 incl self-loop).
__global__ void k_scan1(const int* __restrict__ deg, float* __restrict__ dinv,
                        int* __restrict__ rp, int* __restrict__ bsum) {
    __shared__ int s[256];
    int t = threadIdx.x, i = blockIdx.x * 256 + t;
    int ts = (i < NN) ? (deg[i] + 1) : 0;
    int vp = (i < NN) ? ((ts + 7) & ~7) : 0;
    if (i < NN) dinv[i] = rsqrtf((float)ts);
    s[t] = vp; __syncthreads();
    for (int off = 1; off < 256; off <<= 1) {
        int x = (t >= off) ? s[t - off] : 0;
        __syncthreads();
        s[t] += x;
        __syncthreads();
    }
    if (i < NN) rp[i] = s[t] - vp;          // exclusive (padded)
    if (t == 255) bsum[blockIdx.x] = s[255];
}

// fused scan2+scan3 + pad-slot fill + self-loop write + hsT zero-row init.
__global__ void k_scan23(int* __restrict__ rp, const int* __restrict__ bs,
                         const int* __restrict__ deg, int* __restrict__ col,
                         ushort* __restrict__ hsT) {
    __shared__ int s[256];
    int t = threadIdx.x;
    int v = (t < 196) ? bs[t] : 0;
    s[t] = v; __syncthreads();
    for (int off = 1; off < 256; off <<= 1) {
        int x = (t >= off) ? s[t - off] : 0;
        __syncthreads();
        s[t] += x;
        __syncthreads();
    }
    __shared__ int ps[256];
    ps[t] = s[t] - v;                        // exclusive
    __syncthreads();
    int add = ps[blockIdx.x];
    int i = blockIdx.x * 256 + t;
    if (i < NN) {
        int rpi = rp[i] + add;
        rp[i] = rpi;
        int ts = deg[i] + 1;
        int P = (ts + 7) & ~7;
        col[rpi] = i;                        // self-loop in slot 0, no atomic
        for (int j = ts; j < P; ++j) col[rpi + j] = NN;   // pads -> zero row
    }
    if (blockIdx.x == 0) {
        if (t == 255) rp[NN] = s[255];       // total padded size
        if (t < 64) ((uint*)(hsT + (size_t)NN * DD))[t] = 0;   // zero row
    }
}

// CSR scatter, edges only. deg consumed as countdown: old value in [1..E]
// maps to slots rp[d]+1 .. rp[d]+E (slot 0 = self-loop).
__global__ void k_scatter(const int* __restrict__ srcv, const int* __restrict__ dstv,
                          const int* __restrict__ rp, int* __restrict__ deg,
                          int* __restrict__ col) {
    int t = blockIdx.x * 256 + threadIdx.x;
    if (t < NE) {
        int s = srcv[t], d = dstv[t];
        int pos = rp[d] + atomicSub(&deg[d], 1);
        col[pos] = s;
    }
}

// ---------------- MFMA GEMM ----------------
// out[r][c] = bf16( (X[r][:] @ W[:][c]) * dinv[r] )
// N split across blockIdx.y (2 halves of 64 cols); 32 KB LDS for W frags,
// reused post-barrier to stage C for coalesced float4 stores.
#define CST 72   // C-stage LDS row stride in shorts
template <int INF32>
__global__ __launch_bounds__(256) void k_gemm_mfma(const void* __restrict__ Xv,
                                                   const short* __restrict__ wpk,
                                                   const float* __restrict__ dinv,
                                                   ushort* __restrict__ out) {
    __shared__ short lds[16384];   // W: hi [0,8192), lo [8192,16384); C-stage reuse
    const int t = threadIdx.x;
    const int yb = blockIdx.y * 8192;
    #pragma unroll
    for (int m = 0; m < 4; ++m) {
        int idx = (m * 256 + t) * 8;
        *(float4*)&lds[idx] = *(const float4*)&wpk[yb + idx];
        *(float4*)&lds[8192 + idx] = *(const float4*)&wpk[16384 + yb + idx];
    }

    const int wv = t >> 6, lane = t & 63;
    const int quad = lane >> 4, l16 = lane & 15;
    const int r0 = blockIdx.x * 128 + wv * 32;

    short8 aH[2][4], aL[2][4];
    #pragma unroll
    for (int s = 0; s < 2; ++s) {
        int row = r0 + s * 16 + l16;
        #pragma unroll
        for (int kk = 0; kk < 4; ++kk) {
            int koff = kk * 32 + quad * 8;
            if (INF32) {
                float4 x0 = make_float4(0.f, 0.f, 0.f, 0.f), x1 = x0;
                if (row < NN) {
                    const float* p = (const float*)Xv + (size_t)row * DD + koff;
                    x0 = *(const float4*)p; x1 = *(const float4*)(p + 4);
                }
                float xs[8] = {x0.x, x0.y, x0.z, x0.w, x1.x, x1.y, x1.z, x1.w};
                short8 h, l;
                #pragma unroll
                for (int j = 0; j < 8; ++j) {
                    ushort hb = f2bf(xs[j]);
                    h[j] = (short)hb;
                    l[j] = (short)f2bf(xs[j] - bf2f(hb));
                }
                aH[s][kk] = h; aL[s][kk] = l;
            } else {
                short8 h = {0, 0, 0, 0, 0, 0, 0, 0};
                if (row < NN)
                    h = *(const short8*)((const ushort*)Xv + (size_t)row * DD + koff);
                aH[s][kk] = h;
            }
        }
    }
    __syncthreads();

    float dv[2][4];
    #pragma unroll
    for (int s = 0; s < 2; ++s)
        #pragma unroll
        for (int i = 0; i < 4; ++i) {
            int row = r0 + s * 16 + quad * 4 + i;
            dv[s][i] = (row < NN) ? dinv[row] : 0.f;
        }

    f4 acc[2][4];
    #pragma unroll
    for (int s = 0; s < 2; ++s)
        #pragma unroll
        for (int nt = 0; nt < 4; ++nt)
            acc[s][nt] = (f4){0.f, 0.f, 0.f, 0.f};

    #pragma unroll
    for (int nt = 0; nt < 4; ++nt) {
        #pragma unroll
        for (int kk = 0; kk < 4; ++kk) {
            int fi = ((nt * 4 + kk) * 64 + lane) * 8;
            short8 bh = *(const short8*)&lds[fi];
            short8 bl = *(const short8*)&lds[8192 + fi];
            acc[0][nt] = __builtin_amdgcn_mfma_f32_16x16x32_bf16(aH[0][kk], bh, acc[0][nt], 0, 0, 0);
            acc[0][nt] = __builtin_amdgcn_mfma_f32_16x16x32_bf16(aH[0][kk], bl, acc[0][nt], 0, 0, 0);
            acc[1][nt] = __builtin_amdgcn_mfma_f32_16x16x32_bf16(aH[1][kk], bh, acc[1][nt], 0, 0, 0);
            acc[1][nt] = __builtin_amdgcn_mfma_f32_16x16x32_bf16(aH[1][kk], bl, acc[1][nt], 0, 0, 0);
            if (INF32) {
                acc[0][nt] = __builtin_amdgcn_mfma_f32_16x16x32_bf16(aL[0][kk], bh, acc[0][nt], 0, 0, 0);
                acc[1][nt] = __builtin_amdgcn_mfma_f32_16x16x32_bf16(aL[1][kk], bh, acc[1][nt], 0, 0, 0);
            }
        }
    }

    __syncthreads();   // reuse LDS for C stage
    #pragma unroll
    for (int s = 0; s < 2; ++s) {
        int lr = wv * 32 + s * 16 + quad * 4;
        #pragma unroll
        for (int nt = 0; nt < 4; ++nt)
            #pragma unroll
            for (int i = 0; i < 4; ++i)
                lds[(lr + i) * CST + nt * 16 + l16] = (short)f2bf(acc[s][nt][i] * dv[s][i]);
    }
    __syncthreads();

    int row = t >> 1, half = t & 1;
    int grow = blockIdx.x * 128 + row;
    if (grow < NN) {
        #pragma unroll
        for (int j = 0; j < 4; ++j) {
            float4 v = *(float4*)&lds[row * CST + half * 32 + j * 8];
            *(float4*)&out[(size_t)grow * DD + blockIdx.y * 64 + half * 32 + j * 8] = v;
        }
    }
}

// ---------------- aggregation ----------------
// out[i] = maybe_relu( dinv[i] * sum_{p in row i} hs[col[p]] + bias )
// Rows padded to multiples of 8 (pads gather zero row NN): single
// branch-light 8-wide stream. Wave per node, lane = 1 dword (2 dims).
// All outputs bf16 (consumed by next gemm / bf16 pool).
template <int RELU>
__global__ __launch_bounds__(256) void k_agg(const ushort* __restrict__ hs,
                                             const int* __restrict__ col,
                                             const int* __restrict__ rp,
                                             const float* __restrict__ dinv,
                                             const float* __restrict__ bias,
                                             ushort* __restrict__ outv) {
    int w = threadIdx.x >> 6, lane = threadIdx.x & 63;
    int i = blockIdx.x * 4 + w;
    if (i >= NN) return;
    int p0 = rp[i], p1 = rp[i + 1];
    int d = lane * 2;
    const ushort* hsd = hs + d;
    float x0 = 0.f, y0 = 0.f, x1 = 0.f, y1 = 0.f;
    float x2 = 0.f, y2 = 0.f, x3 = 0.f, y3 = 0.f;
    for (int p = p0; p < p1; p += 8) {
        int c0 = col[p],     c1 = col[p + 1], c2 = col[p + 2], c3 = col[p + 3];
        int c4 = col[p + 4], c5 = col[p + 5], c6 = col[p + 6], c7 = col[p + 7];
        uint v0 = *(const uint*)(hsd + (size_t)c0 * DD);
        uint v1 = *(const uint*)(hsd + (size_t)c1 * DD);
        uint v2 = *(const uint*)(hsd + (size_t)c2 * DD);
        uint v3 = *(const uint*)(hsd + (size_t)c3 * DD);
        uint v4 = *(const uint*)(hsd + (size_t)c4 * DD);
        uint v5 = *(const uint*)(hsd + (size_t)c5 * DD);
        uint v6 = *(const uint*)(hsd + (size_t)c6 * DD);
        uint v7 = *(const uint*)(hsd + (size_t)c7 * DD);
        x0 += bf_lo(v0); y0 += bf_hi(v0); x1 += bf_lo(v1); y1 += bf_hi(v1);
        x2 += bf_lo(v2); y2 += bf_hi(v2); x3 += bf_lo(v3); y3 += bf_hi(v3);
        x0 += bf_lo(v4); y0 += bf_hi(v4); x1 += bf_lo(v5); y1 += bf_hi(v5);
        x2 += bf_lo(v6); y2 += bf_hi(v6); x3 += bf_lo(v7); y3 += bf_hi(v7);
    }
    float ax = (x0 + x1) + (x2 + x3);
    float ay = (y0 + y1) + (y2 + y3);
    float s = dinv[i];
    float2 bb = *(const float2*)(bias + d);
    float ox = fmaf(s, ax, bb.x), oy = fmaf(s, ay, bb.y);
    if (RELU) { ox = fmaxf(ox, 0.f); oy = fmaxf(oy, 0.f); }
    ushort2 o; o.x = f2bf(ox); o.y = f2bf(oy);
    *(ushort2*)(outv + (size_t)i * DD + d) = o;
}

// ---------------- pool ----------------
// batch sorted: 782 blocks x 128 dims, run-length accumulate per 64-node
// chunk (bf16 input), one atomicAdd per (graph transition, dim).
__global__ __launch_bounds__(128) void k_pool(const ushort* __restrict__ h,
                                              const int* __restrict__ batch,
                                              float* __restrict__ sums,
                                              float* __restrict__ cnt) {
    int d = threadIdx.x;  // 0..127
    int start = blockIdx.x * 64;
    if (start >= NN) return;
    int end = min(start + 64, NN);
    float acc = 0.f, c = 0.f;
    int g = batch[start];
    for (int i = start; i < end; ++i) {
        int gi = batch[i];
        if (gi != g) {
            atomicAdd(&sums[g * DD + d], acc);
            if (d == 0) atomicAdd(&cnt[g], c);
            acc = 0.f; c = 0.f; g = gi;
        }
        acc += bf2f(h[(size_t)i * DD + d]);
        c += 1.f;
    }
    atomicAdd(&sums[g * DD + d], acc);
    if (d == 0) atomicAdd(&cnt[g], c);
}

__global__ void k_final(const float* __restrict__ sums, const float* __restrict__ cnt,
                        float* __restrict__ out) {
    int i = blockIdx.x * 256 + threadIdx.x;  // < NG*DD = 8192
    int g = i >> 7;
    out[i] = sums[i] / fmaxf(cnt[g], 1.f);
}

// ---------------- launch ----------------

extern "C" void kernel_launch(void* const* d_in, const int* in_sizes, int n_in,
                              void* d_out, int out_size, void* d_ws, size_t ws_size,
                              hipStream_t stream) {
    (void)in_sizes; (void)n_in; (void)out_size; (void)ws_size;
    const float* x  = (const float*)d_in[0];
    const int*   ei = (const int*)d_in[1];
    const int*   bt = (const int*)d_in[2];
    const float* W1 = (const float*)d_in[3];
    const float* b1 = (const float*)d_in[4];
    const float* W2 = (const float*)d_in[5];
    const float* b2 = (const float*)d_in[6];
    const float* W3 = (const float*)d_in[7];
    const float* b3 = (const float*)d_in[8];
    float* out = (float*)d_out;
    char* ws = (char*)d_ws;

    size_t o = 0;
    auto alloc = [&](size_t bytes) { size_t r = o; o = (o + bytes + 511) & ~(size_t)511; return r; };
    // zeroed region: deg + pool + cnt (one memset)
    int*    deg  = (int*)(ws + alloc((size_t)NN * 4));
    float*  pool = (float*)(ws + alloc((size_t)(NG * DD + NG) * 4));
    float*  cnt  = pool + NG * DD;
    size_t zbytes = o;
    float*  dinv = (float*)(ws + alloc((size_t)NN * 4));
    int*    rp   = (int*)(ws + alloc((size_t)(NN + 1) * 4));
    int*    bs   = (int*)(ws + alloc(256 * 4));
    int*    col  = (int*)(ws + alloc((size_t)(NE + 8 * NN) * 4));   // padded CSR
    short*  wpk  = (short*)(ws + alloc((size_t)3 * 32768 * 2));
    ushort* hsT  = (ushort*)(ws + alloc((size_t)(NN + 1) * DD * 2)); // +1 zero row
    ushort* hsA  = (ushort*)(ws + alloc((size_t)NN * DD * 2));

    const int* srcv = ei;        // edge_index[0]
    const int* dstv = ei + NE;   // edge_index[1]

    hipMemsetAsync(ws, 0, zbytes, stream);

    k_hist_wpack<<<610, 256, 0, stream>>>(dstv, deg, W1, W2, W3, wpk);
    k_scan1<<<196, 256, 0, stream>>>(deg, dinv, rp, bs);
    k_scan23<<<196, 256, 0, stream>>>(rp, bs, deg, col, hsT);
    k_scatter<<<(NE + 255) / 256, 256, 0, stream>>>(srcv, dstv, rp, deg, col);

    const dim3 gG((NN + 127) / 128, 2);   // 391 x 2
    k_gemm_mfma<1><<<gG, 256, 0, stream>>>(x, wpk, dinv, hsT);
    k_agg<1><<<12500, 256, 0, stream>>>(hsT, col, rp, dinv, b1, hsA);
    k_gemm_mfma<0><<<gG, 256, 0, stream>>>(hsA, wpk + 32768, dinv, hsT);
    k_agg<1><<<12500, 256, 0, stream>>>(hsT, col, rp, dinv, b2, hsA);
    k_gemm_mfma<0><<<gG, 256, 0, stream>>>(hsA, wpk + 65536, dinv, hsT);
    k_agg<0><<<12500, 256, 0, stream>>>(hsT, col, rp, dinv, b3, hsA);  // bf16 F

    k_pool<<<(NN + 63) / 64, 128, 0, stream>>>(hsA, bt, pool, cnt);
    k_final<<<(NG * DD) / 256, 256, 0, stream>>>(pool, cnt, out);
}

// Round 13
// 292.314 us; speedup vs baseline: 1.0108x; 1.0108x over previous
//
#include <hip/hip_runtime.h>

#define NN 50000
#define NE 600000
#define DD 128
#define NG 64

typedef unsigned int uint;
typedef unsigned short ushort;
typedef __attribute__((ext_vector_type(8))) short short8;
typedef __attribute__((ext_vector_type(4))) float f4;

// ---------------- bf16 helpers ----------------

__device__ __forceinline__ float bf_lo(uint v) { return __uint_as_float(v << 16); }
__device__ __forceinline__ float bf_hi(uint v) { return __uint_as_float(v & 0xffff0000u); }
__device__ __forceinline__ float bf2f(ushort h) { return __uint_as_float((uint)h << 16); }
__device__ __forceinline__ ushort f2bf(float f) {
    uint u = __float_as_uint(f);
    uint r = (u + 0x7fffu + ((u >> 16) & 1u)) >> 16;   // round-nearest-even
    return (ushort)r;
}

// ---------------- setup kernels ----------------

// blocks [0,2344): degree histogram. blocks [2344,2368): pack W (split bf16
// hi/lo into MFMA B-fragment layout).
__global__ void k_hist_wpack(const int* __restrict__ dstv, int* __restrict__ deg,
                             const float* __restrict__ W1, const float* __restrict__ W2,
                             const float* __restrict__ W3, short* __restrict__ wpk) {
    if (blockIdx.x < 2344) {
        int e = blockIdx.x * 256 + threadIdx.x;
        if (e < NE) atomicAdd(&deg[dstv[e]], 1);
    } else {
        int u = (blockIdx.x - 2344) * 256 + threadIdx.x;   // < 6144
        int layer = u >> 11, g = u & 2047;
        const float* W = (layer == 0) ? W1 : (layer == 1) ? W2 : W3;
        short* base = wpk + (size_t)layer * 32768;
        int nt = g >> 8, kk = (g >> 6) & 3, lane = g & 63;
        int k0 = kk * 32 + (lane >> 4) * 8;
        int n = nt * 16 + (lane & 15);
        #pragma unroll
        for (int j = 0; j < 8; ++j) {
            float w = W[(size_t)(k0 + j) * DD + n];
            ushort h = f2bf(w);
            base[g * 8 + j] = (short)h;
            base[16384 + g * 8 + j] = (short)f2bf(w - bf2f(h));
        }
    }
}

// Rows padded to multiples of 8 (pad cols -> zero row NN). rp is over PADDED
// sizes; dinv over true size (deg+1 incl self-loop).
__global__ void k_scan1(const int* __restrict__ deg, float* __restrict__ dinv,
                        int* __restrict__ rp, int* __restrict__ bsum) {
    __shared__ int s[256];
    int t = threadIdx.x, i = blockIdx.x * 256 + t;
    int ts = (i < NN) ? (deg[i] + 1) : 0;
    int vp = (i < NN) ? ((ts + 7) & ~7) : 0;
    if (i < NN) dinv[i] = rsqrtf((float)ts);
    s[t] = vp; __syncthreads();
    for (int off = 1; off < 256; off <<= 1) {
        int x = (t >= off) ? s[t - off] : 0;
        __syncthreads();
        s[t] += x;
        __syncthreads();
    }
    if (i < NN) rp[i] = s[t] - vp;          // exclusive (padded)
    if (t == 255) bsum[blockIdx.x] = s[255];
}

// fused scan2+scan3 + pad-slot fill + self-loop write + hsT zero-row init.
__global__ void k_scan23(int* __restrict__ rp, const int* __restrict__ bs,
                         const int* __restrict__ deg, int* __restrict__ col,
                         ushort* __restrict__ hsT) {
    __shared__ int s[256];
    int t = threadIdx.x;
    int v = (t < 196) ? bs[t] : 0;
    s[t] = v; __syncthreads();
    for (int off = 1; off < 256; off <<= 1) {
        int x = (t >= off) ? s[t - off] : 0;
        __syncthreads();
        s[t] += x;
        __syncthreads();
    }
    __shared__ int ps[256];
    ps[t] = s[t] - v;                        // exclusive
    __syncthreads();
    int add = ps[blockIdx.x];
    int i = blockIdx.x * 256 + t;
    if (i < NN) {
        int rpi = rp[i] + add;
        rp[i] = rpi;
        int ts = deg[i] + 1;
        int P = (ts + 7) & ~7;
        col[rpi] = i;                        // self-loop in slot 0, no atomic
        for (int j = ts; j < P; ++j) col[rpi + j] = NN;   // pads -> zero row
    }
    if (blockIdx.x == 0) {
        if (t == 255) rp[NN] = s[255];       // total padded size
        if (t < 64) ((uint*)(hsT + (size_t)NN * DD))[t] = 0;   // zero row
    }
}

// CSR scatter, edges only. deg consumed as countdown: old value in [1..E]
// maps to slots rp[d]+1 .. rp[d]+E (slot 0 = self-loop).
__global__ void k_scatter(const int* __restrict__ srcv, const int* __restrict__ dstv,
                          const int* __restrict__ rp, int* __restrict__ deg,
                          int* __restrict__ col) {
    int t = blockIdx.x * 256 + threadIdx.x;
    if (t < NE) {
        int s = srcv[t], d = dstv[t];
        int pos = rp[d] + atomicSub(&deg[d], 1);
        col[pos] = s;
    }
}

// ---------------- MFMA GEMM ----------------
// out[r][c] = bf16( (X[r][:] @ W[:][c]) * dinv[r] )
// N split across blockIdx.y (2 halves of 64 cols); 32 KB LDS for W frags,
// reused post-barrier to stage C for coalesced float4 stores.
#define CST 72   // C-stage LDS row stride in shorts
template <int INF32>
__global__ __launch_bounds__(256) void k_gemm_mfma(const void* __restrict__ Xv,
                                                   const short* __restrict__ wpk,
                                                   const float* __restrict__ dinv,
                                                   ushort* __restrict__ out) {
    __shared__ short lds[16384];   // W: hi [0,8192), lo [8192,16384); C-stage reuse
    const int t = threadIdx.x;
    const int yb = blockIdx.y * 8192;
    #pragma unroll
    for (int m = 0; m < 4; ++m) {
        int idx = (m * 256 + t) * 8;
        *(float4*)&lds[idx] = *(const float4*)&wpk[yb + idx];
        *(float4*)&lds[8192 + idx] = *(const float4*)&wpk[16384 + yb + idx];
    }

    const int wv = t >> 6, lane = t & 63;
    const int quad = lane >> 4, l16 = lane & 15;
    const int r0 = blockIdx.x * 128 + wv * 32;

    short8 aH[2][4], aL[2][4];
    #pragma unroll
    for (int s = 0; s < 2; ++s) {
        int row = r0 + s * 16 + l16;
        #pragma unroll
        for (int kk = 0; kk < 4; ++kk) {
            int koff = kk * 32 + quad * 8;
            if (INF32) {
                float4 x0 = make_float4(0.f, 0.f, 0.f, 0.f), x1 = x0;
                if (row < NN) {
                    const float* p = (const float*)Xv + (size_t)row * DD + koff;
                    x0 = *(const float4*)p; x1 = *(const float4*)(p + 4);
                }
                float xs[8] = {x0.x, x0.y, x0.z, x0.w, x1.x, x1.y, x1.z, x1.w};
                short8 h, l;
                #pragma unroll
                for (int j = 0; j < 8; ++j) {
                    ushort hb = f2bf(xs[j]);
                    h[j] = (short)hb;
                    l[j] = (short)f2bf(xs[j] - bf2f(hb));
                }
                aH[s][kk] = h; aL[s][kk] = l;
            } else {
                short8 h = {0, 0, 0, 0, 0, 0, 0, 0};
                if (row < NN)
                    h = *(const short8*)((const ushort*)Xv + (size_t)row * DD + koff);
                aH[s][kk] = h;
            }
        }
    }
    __syncthreads();

    float dv[2][4];
    #pragma unroll
    for (int s = 0; s < 2; ++s)
        #pragma unroll
        for (int i = 0; i < 4; ++i) {
            int row = r0 + s * 16 + quad * 4 + i;
            dv[s][i] = (row < NN) ? dinv[row] : 0.f;
        }

    f4 acc[2][4];
    #pragma unroll
    for (int s = 0; s < 2; ++s)
        #pragma unroll
        for (int nt = 0; nt < 4; ++nt)
            acc[s][nt] = (f4){0.f, 0.f, 0.f, 0.f};

    #pragma unroll
    for (int nt = 0; nt < 4; ++nt) {
        #pragma unroll
        for (int kk = 0; kk < 4; ++kk) {
            int fi = ((nt * 4 + kk) * 64 + lane) * 8;
            short8 bh = *(const short8*)&lds[fi];
            short8 bl = *(const short8*)&lds[8192 + fi];
            acc[0][nt] = __builtin_amdgcn_mfma_f32_16x16x32_bf16(aH[0][kk], bh, acc[0][nt], 0, 0, 0);
            acc[0][nt] = __builtin_amdgcn_mfma_f32_16x16x32_bf16(aH[0][kk], bl, acc[0][nt], 0, 0, 0);
            acc[1][nt] = __builtin_amdgcn_mfma_f32_16x16x32_bf16(aH[1][kk], bh, acc[1][nt], 0, 0, 0);
            acc[1][nt] = __builtin_amdgcn_mfma_f32_16x16x32_bf16(aH[1][kk], bl, acc[1][nt], 0, 0, 0);
            if (INF32) {
                acc[0][nt] = __builtin_amdgcn_mfma_f32_16x16x32_bf16(aL[0][kk], bh, acc[0][nt], 0, 0, 0);
                acc[1][nt] = __builtin_amdgcn_mfma_f32_16x16x32_bf16(aL[1][kk], bh, acc[1][nt], 0, 0, 0);
            }
        }
    }

    __syncthreads();   // reuse LDS for C stage
    #pragma unroll
    for (int s = 0; s < 2; ++s) {
        int lr = wv * 32 + s * 16 + quad * 4;
        #pragma unroll
        for (int nt = 0; nt < 4; ++nt)
            #pragma unroll
            for (int i = 0; i < 4; ++i)
                lds[(lr + i) * CST + nt * 16 + l16] = (short)f2bf(acc[s][nt][i] * dv[s][i]);
    }
    __syncthreads();

    int row = t >> 1, half = t & 1;
    int grow = blockIdx.x * 128 + row;
    if (grow < NN) {
        #pragma unroll
        for (int j = 0; j < 4; ++j) {
            float4 v = *(float4*)&lds[row * CST + half * 32 + j * 8];
            *(float4*)&out[(size_t)grow * DD + blockIdx.y * 64 + half * 32 + j * 8] = v;
        }
    }
}

// ---------------- aggregation ----------------
// out[i] = maybe_relu( dinv[i] * sum_{p in row i} hs[col[p]] + bias )
// Rows padded to multiples of 8 (pads gather the zero row NN): single
// branch-light 8-wide stream. Wave per node, lane = 1 dword (2 dims).
template <int RELU, int OUTF32>
__global__ __launch_bounds__(256) void k_agg(const ushort* __restrict__ hs,
                                             const int* __restrict__ col,
                                             const int* __restrict__ rp,
                                             const float* __restrict__ dinv,
                                             const float* __restrict__ bias,
                                             void* __restrict__ outv) {
    int w = threadIdx.x >> 6, lane = threadIdx.x & 63;
    int i = blockIdx.x * 4 + w;
    if (i >= NN) return;
    int p0 = rp[i], p1 = rp[i + 1];
    int d = lane * 2;
    const ushort* hsd = hs + d;
    float x0 = 0.f, y0 = 0.f, x1 = 0.f, y1 = 0.f;
    float x2 = 0.f, y2 = 0.f, x3 = 0.f, y3 = 0.f;
    for (int p = p0; p < p1; p += 8) {
        int c0 = col[p],     c1 = col[p + 1], c2 = col[p + 2], c3 = col[p + 3];
        int c4 = col[p + 4], c5 = col[p + 5], c6 = col[p + 6], c7 = col[p + 7];
        uint v0 = *(const uint*)(hsd + (size_t)c0 * DD);
        uint v1 = *(const uint*)(hsd + (size_t)c1 * DD);
        uint v2 = *(const uint*)(hsd + (size_t)c2 * DD);
        uint v3 = *(const uint*)(hsd + (size_t)c3 * DD);
        uint v4 = *(const uint*)(hsd + (size_t)c4 * DD);
        uint v5 = *(const uint*)(hsd + (size_t)c5 * DD);
        uint v6 = *(const uint*)(hsd + (size_t)c6 * DD);
        uint v7 = *(const uint*)(hsd + (size_t)c7 * DD);
        x0 += bf_lo(v0); y0 += bf_hi(v0); x1 += bf_lo(v1); y1 += bf_hi(v1);
        x2 += bf_lo(v2); y2 += bf_hi(v2); x3 += bf_lo(v3); y3 += bf_hi(v3);
        x0 += bf_lo(v4); y0 += bf_hi(v4); x1 += bf_lo(v5); y1 += bf_hi(v5);
        x2 += bf_lo(v6); y2 += bf_hi(v6); x3 += bf_lo(v7); y3 += bf_hi(v7);
    }
    float ax = (x0 + x1) + (x2 + x3);
    float ay = (y0 + y1) + (y2 + y3);
    float s = dinv[i];
    float2 bb = *(const float2*)(bias + d);
    float ox = fmaf(s, ax, bb.x), oy = fmaf(s, ay, bb.y);
    if (RELU) { ox = fmaxf(ox, 0.f); oy = fmaxf(oy, 0.f); }
    if (OUTF32) {
        *(float2*)((float*)outv + (size_t)i * DD + d) = make_float2(ox, oy);
    } else {
        ushort2 o; o.x = f2bf(ox); o.y = f2bf(oy);
        *(ushort2*)((ushort*)outv + (size_t)i * DD + d) = o;
    }
}

// ---------------- pool ----------------
// batch sorted: 782 blocks x 128 dims, run-length accumulate per 64-node
// chunk, one atomicAdd per (graph transition, dim).
__global__ __launch_bounds__(128) void k_pool(const float* __restrict__ h,
                                              const int* __restrict__ batch,
                                              float* __restrict__ sums,
                                              float* __restrict__ cnt) {
    int d = threadIdx.x;  // 0..127
    int start = blockIdx.x * 64;
    if (start >= NN) return;
    int end = min(start + 64, NN);
    float acc = 0.f, c = 0.f;
    int g = batch[start];
    for (int i = start; i < end; ++i) {
        int gi = batch[i];
        if (gi != g) {
            atomicAdd(&sums[g * DD + d], acc);
            if (d == 0) atomicAdd(&cnt[g], c);
            acc = 0.f; c = 0.f; g = gi;
        }
        acc += h[(size_t)i * DD + d];
        c += 1.f;
    }
    atomicAdd(&sums[g * DD + d], acc);
    if (d == 0) atomicAdd(&cnt[g], c);
}

__global__ void k_final(const float* __restrict__ sums, const float* __restrict__ cnt,
                        float* __restrict__ out) {
    int i = blockIdx.x * 256 + threadIdx.x;  // < NG*DD = 8192
    int g = i >> 7;
    out[i] = sums[i] / fmaxf(cnt[g], 1.f);
}

// ---------------- launch ----------------

extern "C" void kernel_launch(void* const* d_in, const int* in_sizes, int n_in,
                              void* d_out, int out_size, void* d_ws, size_t ws_size,
                              hipStream_t stream) {
    (void)in_sizes; (void)n_in; (void)out_size; (void)ws_size;
    const float* x  = (const float*)d_in[0];
    const int*   ei = (const int*)d_in[1];
    const int*   bt = (const int*)d_in[2];
    const float* W1 = (const float*)d_in[3];
    const float* b1 = (const float*)d_in[4];
    const float* W2 = (const float*)d_in[5];
    const float* b2 = (const float*)d_in[6];
    const float* W3 = (const float*)d_in[7];
    const float* b3 = (const float*)d_in[8];
    float* out = (float*)d_out;
    char* ws = (char*)d_ws;

    size_t o = 0;
    auto alloc = [&](size_t bytes) { size_t r = o; o = (o + bytes + 511) & ~(size_t)511; return r; };
    // zeroed region: deg + pool + cnt (one memset)
    int*    deg  = (int*)(ws + alloc((size_t)NN * 4));
    float*  pool = (float*)(ws + alloc((size_t)(NG * DD + NG) * 4));
    float*  cnt  = pool + NG * DD;
    size_t zbytes = o;
    float*  dinv = (float*)(ws + alloc((size_t)NN * 4));
    int*    rp   = (int*)(ws + alloc((size_t)(NN + 1) * 4));
    int*    bs   = (int*)(ws + alloc(256 * 4));
    int*    col  = (int*)(ws + alloc((size_t)(NE + 8 * NN) * 4));   // padded CSR
    short*  wpk  = (short*)(ws + alloc((size_t)3 * 32768 * 2));
    ushort* hsT  = (ushort*)(ws + alloc((size_t)(NN + 1) * DD * 2)); // +1 zero row
    ushort* hsA  = (ushort*)(ws + alloc((size_t)NN * DD * 2));
    float*  F    = (float*)(ws + alloc((size_t)NN * DD * 4));

    const int* srcv = ei;        // edge_index[0]
    const int* dstv = ei + NE;   // edge_index[1]

    hipMemsetAsync(ws, 0, zbytes, stream);

    k_hist_wpack<<<2368, 256, 0, stream>>>(dstv, deg, W1, W2, W3, wpk);
    k_scan1<<<196, 256, 0, stream>>>(deg, dinv, rp, bs);
    k_scan23<<<196, 256, 0, stream>>>(rp, bs, deg, col, hsT);
    k_scatter<<<(NE + 255) / 256, 256, 0, stream>>>(srcv, dstv, rp, deg, col);

    const dim3 gG((NN + 127) / 128, 2);   // 391 x 2
    k_gemm_mfma<1><<<gG, 256, 0, stream>>>(x, wpk, dinv, hsT);
    k_agg<1, 0><<<12500, 256, 0, stream>>>(hsT, col, rp, dinv, b1, hsA);
    k_gemm_mfma<0><<<gG, 256, 0, stream>>>(hsA, wpk + 32768, dinv, hsT);
    k_agg<1, 0><<<12500, 256, 0, stream>>>(hsT, col, rp, dinv, b2, hsA);
    k_gemm_mfma<0><<<gG, 256, 0, stream>>>(hsA, wpk + 65536, dinv, hsT);
    k_agg<0, 1><<<12500, 256, 0, stream>>>(hsT, col, rp, dinv, b3, F);

    k_pool<<<(NN + 63) / 64, 128, 0, stream>>>(F, bt, pool, cnt);
    k_final<<<(NG * DD) / 256, 256, 0, stream>>>(pool, cnt, out);
}